// Round 2
// baseline (2742.276 us; speedup 1.0000x reference)
//
#include <hip/hip_runtime.h>

#define NEGV -1e30f
constexpr int Bn = 64, Tn = 2000, Cn = 256, Ln = 128;

__device__ __forceinline__ float wave_max(float v) {
#pragma unroll
  for (int s = 32; s; s >>= 1) v = fmaxf(v, __shfl_xor(v, s, 64));
  return v;
}
__device__ __forceinline__ float wave_sum(float v) {
#pragma unroll
  for (int s = 32; s; s >>= 1) v += __shfl_xor(v, s, 64);
  return v;
}

// Blocks 0..63: denominator DP for batch b = blockIdx.x (dense bigram FSA).
// Blocks 64..127: numerator DP for batch b = blockIdx.x - 64 (label chain).
__global__ __launch_bounds__(512, 1) void lfmmi_main(
    const float* __restrict__ nnet, const float* __restrict__ trans,
    const int* __restrict__ labels, const int* __restrict__ durs,
    float* __restrict__ den_out, float* __restrict__ num_out) {
  __shared__ float p_lds[Cn];    // p = exp(beta - m), shared broadcast
  __shared__ float psum[512];    // 2-way i-split partial sums
  __shared__ float red[4];       // per-wave reduction scratch
  const int tid = threadIdx.x;
  const int blk = blockIdx.x;

  if (blk < Bn) {
    // ---------------- denominator ----------------
    const int b = blk;
    const int dur = durs[b];
    const int j = tid & (Cn - 1);  // output column
    const int h = tid >> 8;        // i-half: rows [h*128, h*128+128)
    const int wid = tid >> 6;

    // E = exp(trans): column j, 128 rows, packed bf16x2 -> 64 VGPRs
    uint32_t Epk[64];
#pragma unroll
    for (int k = 0; k < 64; ++k) {
      const int i0 = h * 128 + 2 * k;
      const float e0 = __expf(trans[i0 * Cn + j]);
      const float e1 = __expf(trans[(i0 + 1) * Cn + j]);
      const uint32_t u0 = (__float_as_uint(e0) + 0x8000u) >> 16;  // rne bf16
      const uint32_t u1 = (__float_as_uint(e1) + 0x8000u) >> 16;
      Epk[k] = (u0 & 0xffffu) | (u1 << 16);
    }

    const float* xb = nnet + (size_t)b * Tn * Cn;
    float beta = 0.f;
    if (tid < Cn) beta = xb[tid];                      // beta0 = x[0]
    float xnext = (tid < Cn) ? xb[Cn + tid] : 0.f;     // prefetch row t=1

    for (int t = 1; t < dur; ++t) {
      const float xcur = xnext;
      const int tn = (t + 1 < Tn) ? t + 1 : t;
      if (tid < Cn) xnext = xb[(size_t)tn * Cn + tid];  // prefetch next row

      // block max over beta (owners are tid < 256)
      if (tid < Cn) {
        const float wm = wave_max(beta);
        if ((tid & 63) == 0) red[wid] = wm;
      }
      __syncthreads();  // A
      const float mx = fmaxf(fmaxf(red[0], red[1]), fmaxf(red[2], red[3]));
      if (tid < Cn) p_lds[tid] = __expf(beta - mx);
      __syncthreads();  // B

      // matvec: acc_j = sum_i p[i] * E[i][j] over this thread's 128 rows
      const float4* p4 = (const float4*)p_lds + h * 32;
      float a0 = 0.f, a1 = 0.f, a2 = 0.f, a3 = 0.f;
#pragma unroll
      for (int k = 0; k < 32; ++k) {
        const float4 pv = p4[k];
        const uint32_t ua = Epk[2 * k], ub = Epk[2 * k + 1];
        a0 = fmaf(pv.x, __uint_as_float(ua << 16), a0);
        a1 = fmaf(pv.y, __uint_as_float(ua & 0xffff0000u), a1);
        a2 = fmaf(pv.z, __uint_as_float(ub << 16), a2);
        a3 = fmaf(pv.w, __uint_as_float(ub & 0xffff0000u), a3);
      }
      psum[tid] = (a0 + a1) + (a2 + a3);
      __syncthreads();  // C
      if (tid < Cn) {
        const float acc = psum[tid] + psum[tid + Cn];
        beta = mx + __logf(acc) + xcur;
      }
    }

    // den_score = logsumexp_j(beta)
    if (tid < Cn) {
      const float wm = wave_max(beta);
      if ((tid & 63) == 0) red[wid] = wm;
    }
    __syncthreads();
    const float mx = fmaxf(fmaxf(red[0], red[1]), fmaxf(red[2], red[3]));
    const float ev = (tid < Cn) ? __expf(beta - mx) : 0.f;
    __syncthreads();  // reads of red done before reuse
    {
      const float ws = wave_sum(ev);
      if (tid < Cn && (tid & 63) == 0) red[wid] = ws;
    }
    __syncthreads();
    if (tid == 0) {
      const float s = (red[0] + red[1]) + (red[2] + red[3]);
      den_out[b] = mx + __logf(s);
    }
  } else {
    // ---------------- numerator ----------------
    const int b = blk - Bn;
    const int dur = durs[b];
    const int l = tid;
    const float* xb = nnet + (size_t)b * Tn * Cn;
    const int lab = (l < Ln) ? labels[b * Ln + l] : 0;
    float alpha = NEGV;
    if (l == 0) alpha = xb[lab];  // alpha0[0] = emit at t=0
    if (l < Ln) p_lds[l] = alpha;
    // gather-emission prefetch, depth 2
    float e1 = xb[(size_t)1 * Cn + lab];
    float e2 = xb[(size_t)2 * Cn + lab];
    __syncthreads();

    for (int t = 1; t < dur; ++t) {
      const float ecur = e1;
      e1 = e2;
      const int tn = (t + 2 < Tn) ? t + 2 : Tn - 1;
      e2 = xb[(size_t)tn * Cn + lab];

      const float aprev = (l > 0 && l < Ln) ? p_lds[l - 1] : NEGV;
      float anew = 0.f;
      if (l < Ln) {
        const float mxv = fmaxf(alpha, aprev);
        const float d = fminf(alpha, aprev) - mxv;  // <= 0
        anew = mxv + log1pf(__expf(d)) + ecur;      // logaddexp + emit
      }
      __syncthreads();  // all old-alpha reads done
      if (l < Ln) {
        p_lds[l] = anew;
        alpha = anew;
      }
      __syncthreads();  // new alphas visible
    }
    if (l == Ln - 1) num_out[b] = alpha;
  }
}

__global__ void lfmmi_final(const float* __restrict__ den,
                            const float* __restrict__ num,
                            const int* __restrict__ durs,
                            float* __restrict__ out) {
  const int tid = threadIdx.x;  // 64 threads
  float v = num[tid] - den[tid];
  float d = (float)durs[tid];
  v = wave_sum(v);
  d = wave_sum(d);
  if (tid == 0) {
    out[0] = v;
    out[1] = d;
    out[2] = d;
  }
}

extern "C" void kernel_launch(void* const* d_in, const int* in_sizes, int n_in,
                              void* d_out, int out_size, void* d_ws, size_t ws_size,
                              hipStream_t stream) {
  const float* nnet = (const float*)d_in[0];   // (64, 2000, 256) f32
  const float* trans = (const float*)d_in[1];  // (256, 256) f32
  const int* labels = (const int*)d_in[2];     // (64, 128) i32
  const int* durs = (const int*)d_in[3];       // (64,) i32
  float* den_ws = (float*)d_ws;
  float* num_ws = den_ws + Bn;
  lfmmi_main<<<dim3(2 * Bn), dim3(512), 0, stream>>>(nnet, trans, labels, durs,
                                                     den_ws, num_ws);
  lfmmi_final<<<dim3(1), dim3(64), 0, stream>>>(den_ws, num_ws, durs,
                                                (float*)d_out);
}

// Round 3
// 2116.270 us; speedup vs baseline: 1.2958x; 1.2958x over previous
//
#include <hip/hip_runtime.h>

#define NEGV -1e30f
constexpr int Bn = 64, Tn = 2000, Cn = 256, Ln = 128;

typedef float f32x2 __attribute__((ext_vector_type(2)));

__device__ __forceinline__ float wave_max(float v) {
#pragma unroll
  for (int s = 32; s; s >>= 1) v = fmaxf(v, __shfl_xor(v, s, 64));
  return v;
}
__device__ __forceinline__ float wave_sum(float v) {
#pragma unroll
  for (int s = 32; s; s >>= 1) v += __shfl_xor(v, s, 64);
  return v;
}
__device__ __forceinline__ float half_max(float v) {  // reduce within 32-lane half
#pragma unroll
  for (int s = 16; s; s >>= 1) v = fmaxf(v, __shfl_xor(v, s, 64));
  return v;
}

// Blocks 0..63: denominator DP (dense bigram FSA), 512 threads.
// Blocks 64..127: numerator DP (label chain), 1 wave.
__global__ __launch_bounds__(512, 1) void lfmmi_main(
    const float* __restrict__ nnet, const float* __restrict__ trans,
    const int* __restrict__ labels, const int* __restrict__ durs,
    float* __restrict__ den_out, float* __restrict__ num_out) {
  __shared__ __align__(16) float p_lds[2][Cn];  // double-buffered p = exp(beta-m)
  __shared__ float red[2][8];                   // double-buffered wave-max partials
  const int tid = threadIdx.x;
  const int blk = blockIdx.x;

  if (blk < Bn) {
    // ---------------- denominator ----------------
    const int b = blk;
    const int dur = durs[b];
    const int wid = tid >> 6;
    const int lane = tid & 63;
    const int h = lane >> 5;            // i-half: rows [h*128, h*128+128)
    const int j = wid * 32 + (lane & 31);  // output column (0..255)

    // E = exp(trans) column j, this half's 128 rows, f32 pairs in 64 VGPR-pairs
    f32x2 E2[64];
#pragma unroll
    for (int k = 0; k < 64; ++k) {
      const int i0 = h * 128 + 2 * k;
      E2[k][0] = __expf(trans[i0 * Cn + j]);
      E2[k][1] = __expf(trans[(i0 + 1) * Cn + j]);
    }

    const float* xb = nnet + (size_t)b * Tn * Cn;
    float beta = 0.f;
    if (h == 0) beta = xb[j];  // beta0 = x[0]
    float xn1 = (h == 0) ? xb[Cn + j] : 0.f;      // x[1]
    float xn2 = (h == 0) ? xb[2 * Cn + j] : 0.f;  // x[2]

    // exact max(beta0) once; also seeds red[0] for the t=1 pipeline read
    {
      const float wm = half_max(beta);
      if (lane == 0) red[0][wid] = wm;
    }
    __syncthreads();
    float m_use = red[0][0];
#pragma unroll
    for (int w = 1; w < 8; ++w) m_use = fmaxf(m_use, red[0][w]);

    for (int t = 1; t < dur; ++t) {
      const int cur = t & 1;
      if (h == 0) p_lds[cur][j] = __expf(beta - m_use);  // safe: lag-2 max
      const float xcur = xn1;
      xn1 = xn2;
      const int tn = (t + 2 < Tn) ? t + 2 : Tn - 1;
      if (h == 0) xn2 = xb[(size_t)tn * Cn + j];  // prefetch depth 2
      __syncthreads();  // the only barrier per step

      // pipelined max: read partials of beta_{t-2} (hidden under matvec)
      float m_next = red[cur ^ 1][0];
#pragma unroll
      for (int w = 1; w < 8; ++w) m_next = fmaxf(m_next, red[cur ^ 1][w]);
      // produce partials of beta_{t-1} for use at t+2 (off critical path)
      {
        const float wm = half_max(beta);
        if (lane == 0) red[cur][wid] = wm;
      }

      // matvec: this thread's 128 rows x 1 col, 64 v_pk_fma_f32
      const float4* p4 = (const float4*)&p_lds[cur][h * 128];
      f32x2 acc[4];
#pragma unroll
      for (int a = 0; a < 4; ++a) acc[a] = (f32x2){0.f, 0.f};
#pragma unroll
      for (int k = 0; k < 32; ++k) {
        const float4 pv = p4[k];
        f32x2 plo, phi;
        plo[0] = pv.x; plo[1] = pv.y;
        phi[0] = pv.z; phi[1] = pv.w;
        asm("v_pk_fma_f32 %0, %1, %2, %0"
            : "+v"(acc[(2 * k) & 3]) : "v"(plo), "v"(E2[2 * k]));
        asm("v_pk_fma_f32 %0, %1, %2, %0"
            : "+v"(acc[(2 * k + 1) & 3]) : "v"(phi), "v"(E2[2 * k + 1]));
      }
      const f32x2 at = (acc[0] + acc[1]) + (acc[2] + acc[3]);
      float s = at[0] + at[1];
      const float tot = s + __shfl_xor(s, 32, 64);  // combine the two i-halves
      if (h == 0) beta = m_use + __logf(tot) + xcur;
      m_use = m_next;
    }

    // den_score = logsumexp_j(beta)
    if (h == 0) p_lds[0][j] = beta;
    __syncthreads();
    if (tid < 64) {
      const float4 v = ((const float4*)p_lds[0])[tid];
      float mx = fmaxf(fmaxf(v.x, v.y), fmaxf(v.z, v.w));
      mx = wave_max(mx);
      float sm = __expf(v.x - mx) + __expf(v.y - mx) +
                 __expf(v.z - mx) + __expf(v.w - mx);
      sm = wave_sum(sm);
      if (tid == 0) den_out[b] = mx + __logf(sm);
    }
  } else {
    // ---------------- numerator: single wave, no barriers ----------------
    const int b = blk - Bn;
    if (tid >= 64) return;
    const int dur = durs[b];
    const int lane = tid;
    const float* xb = nnet + (size_t)b * Tn * Cn;
    const int lab0 = labels[b * Ln + lane];        // label index lane
    const int lab1 = labels[b * Ln + 64 + lane];   // label index lane+64
    float a0 = (lane == 0) ? xb[lab0] : NEGV;
    float a1 = NEGV;
    // emission prefetch, depth 4 (named regs, static shifts)
    float ea1 = xb[(size_t)1 * Cn + lab0], eb1 = xb[(size_t)1 * Cn + lab1];
    float ea2 = xb[(size_t)2 * Cn + lab0], eb2 = xb[(size_t)2 * Cn + lab1];
    float ea3 = xb[(size_t)3 * Cn + lab0], eb3 = xb[(size_t)3 * Cn + lab1];
    float ea4 = xb[(size_t)4 * Cn + lab0], eb4 = xb[(size_t)4 * Cn + lab1];

    for (int t = 1; t < dur; ++t) {
      const float ec0 = ea1, ec1 = eb1;
      ea1 = ea2; ea2 = ea3; ea3 = ea4;
      eb1 = eb2; eb2 = eb3; eb3 = eb4;
      const int tn = (t + 4 < Tn) ? t + 4 : Tn - 1;
      ea4 = xb[(size_t)tn * Cn + lab0];
      eb4 = xb[(size_t)tn * Cn + lab1];

      const float p0s = __shfl_up(a0, 1, 64);
      const float p1s = __shfl_up(a1, 1, 64);
      const float w63 = __shfl(a0, 63, 64);   // label 63 -> prev of label 64
      const float prev0 = lane ? p0s : NEGV;
      const float prev1 = lane ? p1s : w63;

      const float mx0 = fmaxf(a0, prev0), d0 = fminf(a0, prev0) - mx0;
      const float mx1 = fmaxf(a1, prev1), d1 = fminf(a1, prev1) - mx1;
      a0 = mx0 + log1pf(__expf(d0)) + ec0;
      a1 = mx1 + log1pf(__expf(d1)) + ec1;
    }
    if (lane == 63) num_out[b] = a1;
  }
}

__global__ void lfmmi_final(const float* __restrict__ den,
                            const float* __restrict__ num,
                            const int* __restrict__ durs,
                            float* __restrict__ out) {
  const int tid = threadIdx.x;  // 64 threads
  float v = num[tid] - den[tid];
  float d = (float)durs[tid];
  v = wave_sum(v);
  d = wave_sum(d);
  if (tid == 0) {
    out[0] = v;
    out[1] = d;
    out[2] = d;
  }
}

extern "C" void kernel_launch(void* const* d_in, const int* in_sizes, int n_in,
                              void* d_out, int out_size, void* d_ws, size_t ws_size,
                              hipStream_t stream) {
  const float* nnet = (const float*)d_in[0];   // (64, 2000, 256) f32
  const float* trans = (const float*)d_in[1];  // (256, 256) f32
  const int* labels = (const int*)d_in[2];     // (64, 128) i32
  const int* durs = (const int*)d_in[3];       // (64,) i32
  float* den_ws = (float*)d_ws;
  float* num_ws = den_ws + Bn;
  lfmmi_main<<<dim3(2 * Bn), dim3(512), 0, stream>>>(nnet, trans, labels, durs,
                                                     den_ws, num_ws);
  lfmmi_final<<<dim3(1), dim3(64), 0, stream>>>(den_ws, num_ws, durs,
                                                (float*)d_out);
}

// Round 5
// 1298.658 us; speedup vs baseline: 2.1116x; 1.6296x over previous
//
#include <hip/hip_runtime.h>

#define NEGV -1e30f
constexpr int Bn = 64, Tn = 2000, Cn = 256, Ln = 128;

__device__ __forceinline__ float wave_max(float v) {
#pragma unroll
  for (int s = 32; s; s >>= 1) v = fmaxf(v, __shfl_xor(v, s, 64));
  return v;
}
__device__ __forceinline__ float wave_sum(float v) {
#pragma unroll
  for (int s = 32; s; s >>= 1) v += __shfl_xor(v, s, 64);
  return v;
}
__device__ __forceinline__ unsigned int bf16_rne(float f) {
  return (__float_as_uint(f) + 0x8000u) >> 16;  // round-half-up bf16
}

// Blocks 0..63: denominator DP (dense bigram FSA), 512 threads = 8 waves.
//   wave w owns i-rows [32w, 32w+32); lane owns cols lane*4..lane*4+3.
//   p (=exp(beta-m)) lives in LDS as bf16[256]; E packed bf16x2 in VGPRs;
//   inner loop = v_dot2_f32_bf16. 8-way i-reduce via part[8][256] LDS.
//   m = lag-1 beta[0] (exact log-domain offset, added back; spread<=~16).
// Blocks 64..127: numerator DP (label chain), 1 wave, shuffle-only.
__global__ __launch_bounds__(512, 1) void lfmmi_main(
    const float* __restrict__ nnet, const float* __restrict__ trans,
    const int* __restrict__ labels, const int* __restrict__ durs,
    float* __restrict__ den_out, float* __restrict__ num_out) {
  __shared__ __align__(16) float part[8][Cn];        // 8 KB partial sums
  __shared__ __align__(16) unsigned short p_bf[Cn];  // p in bf16
  __shared__ float m_lds[2];                         // lag-1 beta[0]
  const int tid = threadIdx.x;
  const int blk = blockIdx.x;

  if (blk < Bn) {
    // ---------------- denominator ----------------
    const int b = blk;
    const int dur = durs[b];
    const int w = tid >> 6;    // wave = i-slice
    const int lane = tid & 63; // col group: cols lane*4 .. lane*4+3

    // E packed: Eu[k][c] = bf16x2( E[w*32+2k][lane*4+c], E[w*32+2k+1][...] )
    unsigned int Eu[16][4];
#pragma unroll
    for (int k = 0; k < 16; ++k) {
#pragma unroll
      for (int c = 0; c < 4; ++c) {
        const int i0 = w * 32 + 2 * k;
        const int j = lane * 4 + c;
        const unsigned int lo = bf16_rne(__expf(trans[i0 * Cn + j]));
        const unsigned int hi = bf16_rne(__expf(trans[(i0 + 1) * Cn + j]));
        Eu[k][c] = (lo & 0xffffu) | (hi << 16);
      }
    }

    const float* xb = nnet + (size_t)b * Tn * Cn;
    const bool is_red = (tid < Cn);  // waves 0..3: reducer for col j = tid
    float beta = 0.f, m_carry = 0.f, xn1 = 0.f, xn2 = 0.f;
    if (is_red) {
      beta = xb[tid];       // beta0 = x[0]
      m_carry = xb[0];      // beta0[0] (scalar broadcast)
      p_bf[tid] = (unsigned short)bf16_rne(__expf(beta - m_carry));
      if (tid == 0) m_lds[0] = beta;
      xn1 = xb[Cn + tid];       // x[1][j]
      xn2 = xb[2 * Cn + tid];   // x[2][j]
    }
    __syncthreads();  // p(t=1) visible

    for (int t = 1; t < dur; ++t) {
      const float m_new = is_red ? m_lds[(t - 1) & 1] : 0.f;  // beta0(t-1)

      // p-slice for this wave's 32 rows: 4 x b128 broadcast reads
      union { uint4 q[4]; unsigned int u[16]; } P;
      const uint4* psrc = (const uint4*)&p_bf[w * 32];
      P.q[0] = psrc[0]; P.q[1] = psrc[1]; P.q[2] = psrc[2]; P.q[3] = psrc[3];

      // 64 x v_dot2_f32_bf16: acc[c] += sum over 32 rows of p[i]*E[i][j]
      float acc[4] = {0.f, 0.f, 0.f, 0.f};
#pragma unroll
      for (int k = 0; k < 16; ++k) {
#pragma unroll
        for (int c = 0; c < 4; ++c) {
          asm("v_dot2_f32_bf16 %0, %1, %2, %0"
              : "+v"(acc[c]) : "v"(P.u[k]), "v"(Eu[k][c]));
        }
      }
      *(float4*)&part[w][lane * 4] =
          make_float4(acc[0], acc[1], acc[2], acc[3]);
      __syncthreads();  // partials visible

      if (is_red) {
        float s = part[0][tid];
#pragma unroll
        for (int q = 1; q < 8; ++q) s += part[q][tid];
        beta = m_carry + __logf(s) + xn1;  // adds back the m used in p
        xn1 = xn2;
        const int tn = (t + 2 < Tn) ? t + 2 : Tn - 1;
        xn2 = xb[(size_t)tn * Cn + tid];
        m_carry = m_new;  // m for p(t+1) and for beta(t+1) add-back
        p_bf[tid] = (unsigned short)bf16_rne(__expf(beta - m_carry));
        if (tid == 0) m_lds[t & 1] = beta;  // beta[0](t), read at t+1
      }
      __syncthreads();  // p(t+1) visible; part safe to overwrite
    }

    // den_score = logsumexp_j(beta)
    if (is_red) part[0][tid] = beta;
    __syncthreads();
    if (tid < 64) {
      const float4 v = ((const float4*)part[0])[tid];
      float mx = fmaxf(fmaxf(v.x, v.y), fmaxf(v.z, v.w));
      mx = wave_max(mx);
      float sm = __expf(v.x - mx) + __expf(v.y - mx) +
                 __expf(v.z - mx) + __expf(v.w - mx);
      sm = wave_sum(sm);
      if (tid == 0) den_out[b] = mx + __logf(sm);
    }
  } else {
    // ---------------- numerator: single wave, no barriers ----------------
    const int b = blk - Bn;
    if (tid >= 64) return;
    const int dur = durs[b];
    const int lane = tid;
    const float* xb = nnet + (size_t)b * Tn * Cn;
    const int lab0 = labels[b * Ln + lane];       // label index lane
    const int lab1 = labels[b * Ln + 64 + lane];  // label index lane+64
    float a0 = (lane == 0) ? xb[lab0] : NEGV;
    float a1 = NEGV;
    float ea1 = xb[(size_t)1 * Cn + lab0], eb1 = xb[(size_t)1 * Cn + lab1];
    float ea2 = xb[(size_t)2 * Cn + lab0], eb2 = xb[(size_t)2 * Cn + lab1];
    float ea3 = xb[(size_t)3 * Cn + lab0], eb3 = xb[(size_t)3 * Cn + lab1];
    float ea4 = xb[(size_t)4 * Cn + lab0], eb4 = xb[(size_t)4 * Cn + lab1];

    for (int t = 1; t < dur; ++t) {
      const float ec0 = ea1, ec1 = eb1;
      ea1 = ea2; ea2 = ea3; ea3 = ea4;
      eb1 = eb2; eb2 = eb3; eb3 = eb4;
      const int tn = (t + 4 < Tn) ? t + 4 : Tn - 1;
      ea4 = xb[(size_t)tn * Cn + lab0];
      eb4 = xb[(size_t)tn * Cn + lab1];

      const float p0s = __shfl_up(a0, 1, 64);
      const float p1s = __shfl_up(a1, 1, 64);
      const float w63 = __shfl(a0, 63, 64);  // label 63 -> prev of label 64
      const float prev0 = lane ? p0s : NEGV;
      const float prev1 = lane ? p1s : w63;

      const float mx0 = fmaxf(a0, prev0), d0 = fminf(a0, prev0) - mx0;
      const float mx1 = fmaxf(a1, prev1), d1 = fminf(a1, prev1) - mx1;
      a0 = mx0 + log1pf(__expf(d0)) + ec0;
      a1 = mx1 + log1pf(__expf(d1)) + ec1;
    }
    if (lane == 63) num_out[b] = a1;
  }
}

__global__ void lfmmi_final(const float* __restrict__ den,
                            const float* __restrict__ num,
                            const int* __restrict__ durs,
                            float* __restrict__ out) {
  const int tid = threadIdx.x;  // 64 threads
  float v = num[tid] - den[tid];
  float d = (float)durs[tid];
  v = wave_sum(v);
  d = wave_sum(d);
  if (tid == 0) {
    out[0] = v;
    out[1] = d;
    out[2] = d;
  }
}

extern "C" void kernel_launch(void* const* d_in, const int* in_sizes, int n_in,
                              void* d_out, int out_size, void* d_ws, size_t ws_size,
                              hipStream_t stream) {
  const float* nnet = (const float*)d_in[0];   // (64, 2000, 256) f32
  const float* trans = (const float*)d_in[1];  // (256, 256) f32
  const int* labels = (const int*)d_in[2];     // (64, 128) i32
  const int* durs = (const int*)d_in[3];       // (64,) i32
  float* den_ws = (float*)d_ws;
  float* num_ws = den_ws + Bn;
  lfmmi_main<<<dim3(2 * Bn), dim3(512), 0, stream>>>(nnet, trans, labels, durs,
                                                     den_ws, num_ws);
  lfmmi_final<<<dim3(1), dim3(64), 0, stream>>>(den_ws, num_ws, durs,
                                                (float*)d_out);
}

// Round 6
// 1287.732 us; speedup vs baseline: 2.1295x; 1.0085x over previous
//
#include <hip/hip_runtime.h>

#define NEGV -1e30f
constexpr int Bn = 64, Tn = 2000, Cn = 256, Ln = 128;

__device__ __forceinline__ float wave_max(float v) {
#pragma unroll
  for (int s = 32; s; s >>= 1) v = fmaxf(v, __shfl_xor(v, s, 64));
  return v;
}
__device__ __forceinline__ float wave_sum(float v) {
#pragma unroll
  for (int s = 32; s; s >>= 1) v += __shfl_xor(v, s, 64);
  return v;
}
__device__ __forceinline__ unsigned int bf16_rne(float f) {
  return (__float_as_uint(f) + 0x8000u) >> 16;  // round-half-up bf16
}

// Blocks 0..63: denominator DP (dense bigram FSA), 512 threads = 8 waves.
//   Wave w owns output cols [32w, 32w+32). Lane = (c = lane&31, h = lane>>5):
//   dots rows [128h, 128h+128) of col j=32w+c (64 v_dot2), i-combine via one
//   shfl_xor(32). ONE barrier + ONE LDS round-trip (p) per step.
//   m(t) = beta0(t-2): exact offset (added back), via 2-slot m_lds scalar.
// Blocks 64..127: numerator DP (label chain), 1 wave, shuffle-only.
__global__ __launch_bounds__(512, 1) void lfmmi_main(
    const float* __restrict__ nnet, const float* __restrict__ trans,
    const int* __restrict__ labels, const int* __restrict__ durs,
    float* __restrict__ den_out, float* __restrict__ num_out) {
  __shared__ __align__(16) unsigned short p_bf[2][Cn];  // double-buffered p
  __shared__ __align__(16) float fin[Cn];               // final-LSE scratch
  __shared__ float m_lds[2];                            // beta0 history
  const int tid = threadIdx.x;
  const int blk = blockIdx.x;

  if (blk < Bn) {
    // ---------------- denominator ----------------
    const int b = blk;
    const int dur = durs[b];
    const int w = tid >> 6;       // wave -> col group
    const int lane = tid & 63;
    const int c = lane & 31;      // col within group
    const int h = lane >> 5;      // i-half: rows [128h, 128h+128)
    const int j = w * 32 + c;     // this lane's output column

    // E rows [128h,128h+128) of col j, packed bf16x2 -> 64 VGPRs
    unsigned int Ep[64];
#pragma unroll
    for (int k = 0; k < 64; ++k) {
      const int i0 = 128 * h + 2 * k;
      const unsigned int lo = bf16_rne(__expf(trans[i0 * Cn + j]));
      const unsigned int hi = bf16_rne(__expf(trans[(i0 + 1) * Cn + j]));
      Ep[k] = (lo & 0xffffu) | (hi << 16);
    }

    const float* xb = nnet + (size_t)b * Tn * Cn;
    float beta = xb[j];        // beta(0)[j] (both halves compute identically)
    const float m0 = xb[0];    // beta0(0)
    float m_add = m0;          // m(t) for add-back at current step
    if (h == 0) p_bf[1][j] = (unsigned short)bf16_rne(__expf(beta - m0));
    if (tid == 0) m_lds[0] = m0;
    float xn1 = xb[Cn + j];        // x[1][j]
    float xn2 = xb[2 * Cn + j];    // x[2][j]
    __syncthreads();  // p(1), m_lds[0] visible

    for (int t = 1; t < dur; ++t) {
      const int cur = t & 1;
      const float mn = m_lds[(t - 1) & 1];  // beta0(t-1) = m(t+1)

      // p(t) slice: rows [128h,128h+128) = 16 x b128 (2 unique lines/instr)
      const uint4* ps = (const uint4*)&p_bf[cur][128 * h];
      float a0 = 0.f, a1 = 0.f, a2 = 0.f, a3 = 0.f;
#pragma unroll
      for (int k = 0; k < 16; ++k) {
        const uint4 q = ps[k];
        asm("v_dot2_f32_bf16 %0, %1, %2, %0" : "+v"(a0) : "v"(q.x), "v"(Ep[4 * k + 0]));
        asm("v_dot2_f32_bf16 %0, %1, %2, %0" : "+v"(a1) : "v"(q.y), "v"(Ep[4 * k + 1]));
        asm("v_dot2_f32_bf16 %0, %1, %2, %0" : "+v"(a2) : "v"(q.z), "v"(Ep[4 * k + 2]));
        asm("v_dot2_f32_bf16 %0, %1, %2, %0" : "+v"(a3) : "v"(q.w), "v"(Ep[4 * k + 3]));
      }
      float s = (a0 + a1) + (a2 + a3);
      s += __shfl_xor(s, 32, 64);           // combine the two i-halves
      beta = m_add + __logf(s) + xn1;       // exact add-back of m(t)

      xn1 = xn2;
      const int tn = (t + 2 < Tn) ? t + 2 : Tn - 1;
      xn2 = xb[(size_t)tn * Cn + j];        // prefetch depth 2

      if (h == 0)  // p(t+1) with m(t+1) = beta0(t-1)
        p_bf[cur ^ 1][j] = (unsigned short)bf16_rne(__expf(beta - mn));
      if (tid == 0) m_lds[t & 1] = beta;    // beta0(t), read at t+1
      m_add = mn;
      __syncthreads();  // the only barrier per step
    }

    // den_score = logsumexp_j(beta)
    if (h == 0) fin[j] = beta;
    __syncthreads();
    if (tid < 64) {
      const float4 v = ((const float4*)fin)[tid];
      float mx = fmaxf(fmaxf(v.x, v.y), fmaxf(v.z, v.w));
      mx = wave_max(mx);
      float sm = __expf(v.x - mx) + __expf(v.y - mx) +
                 __expf(v.z - mx) + __expf(v.w - mx);
      sm = wave_sum(sm);
      if (tid == 0) den_out[b] = mx + __logf(sm);
    }
  } else {
    // ---------------- numerator: single wave, no barriers ----------------
    const int b = blk - Bn;
    if (tid >= 64) return;
    const int dur = durs[b];
    const int lane = tid;
    const float* xb = nnet + (size_t)b * Tn * Cn;
    const int lab0 = labels[b * Ln + lane];       // label index lane
    const int lab1 = labels[b * Ln + 64 + lane];  // label index lane+64
    float a0 = (lane == 0) ? xb[lab0] : NEGV;
    float a1 = NEGV;
    float ea1 = xb[(size_t)1 * Cn + lab0], eb1 = xb[(size_t)1 * Cn + lab1];
    float ea2 = xb[(size_t)2 * Cn + lab0], eb2 = xb[(size_t)2 * Cn + lab1];
    float ea3 = xb[(size_t)3 * Cn + lab0], eb3 = xb[(size_t)3 * Cn + lab1];
    float ea4 = xb[(size_t)4 * Cn + lab0], eb4 = xb[(size_t)4 * Cn + lab1];

    for (int t = 1; t < dur; ++t) {
      const float ec0 = ea1, ec1 = eb1;
      ea1 = ea2; ea2 = ea3; ea3 = ea4;
      eb1 = eb2; eb2 = eb3; eb3 = eb4;
      const int tn = (t + 4 < Tn) ? t + 4 : Tn - 1;
      ea4 = xb[(size_t)tn * Cn + lab0];
      eb4 = xb[(size_t)tn * Cn + lab1];

      const float p0s = __shfl_up(a0, 1, 64);
      const float p1s = __shfl_up(a1, 1, 64);
      const float w63 = __shfl(a0, 63, 64);  // label 63 -> prev of label 64
      const float prev0 = lane ? p0s : NEGV;
      const float prev1 = lane ? p1s : w63;

      const float mx0 = fmaxf(a0, prev0), d0 = fminf(a0, prev0) - mx0;
      const float mx1 = fmaxf(a1, prev1), d1 = fminf(a1, prev1) - mx1;
      a0 = mx0 + log1pf(__expf(d0)) + ec0;
      a1 = mx1 + log1pf(__expf(d1)) + ec1;
    }
    if (lane == 63) num_out[b] = a1;
  }
}

__global__ void lfmmi_final(const float* __restrict__ den,
                            const float* __restrict__ num,
                            const int* __restrict__ durs,
                            float* __restrict__ out) {
  const int tid = threadIdx.x;  // 64 threads
  float v = num[tid] - den[tid];
  float d = (float)durs[tid];
  v = wave_sum(v);
  d = wave_sum(d);
  if (tid == 0) {
    out[0] = v;
    out[1] = d;
    out[2] = d;
  }
}

extern "C" void kernel_launch(void* const* d_in, const int* in_sizes, int n_in,
                              void* d_out, int out_size, void* d_ws, size_t ws_size,
                              hipStream_t stream) {
  const float* nnet = (const float*)d_in[0];   // (64, 2000, 256) f32
  const float* trans = (const float*)d_in[1];  // (256, 256) f32
  const int* labels = (const int*)d_in[2];     // (64, 128) i32
  const int* durs = (const int*)d_in[3];       // (64,) i32
  float* den_ws = (float*)d_ws;
  float* num_ws = den_ws + Bn;
  lfmmi_main<<<dim3(2 * Bn), dim3(512), 0, stream>>>(nnet, trans, labels, durs,
                                                     den_ws, num_ws);
  lfmmi_final<<<dim3(1), dim3(64), 0, stream>>>(den_ws, num_ws, durs,
                                                (float*)d_out);
}